// Round 2
// baseline (504.064 us; speedup 1.0000x reference)
//
#include <hip/hip_runtime.h>
#include <math.h>

#define HEADS 8
#define HD 32
#define KNB 32
#define CIN 128
#define COUT 256
#define BB 4
#define NN 8192
#define EPSV 1e-5f
#define SLOPE 0.2f

// ---------------- QKV GEMM ----------------
// x: [B][CIN][N], W: [COUT][CIN]. Output node-major [B][N][COUT].
// grid (N/64, 12, B); y: mat = y>>2 (0=Q,1=K,2=V), co0 = (y&3)*64
__global__ __launch_bounds__(256) void qkv_kernel(
    const float* __restrict__ x,
    const float* __restrict__ Wq, const float* __restrict__ Wk, const float* __restrict__ Wv,
    float* __restrict__ Q, float* __restrict__ K, float* __restrict__ V)
{
    __shared__ float ws[64][65];  // [co][ci]  pad->2-way max conflicts
    __shared__ float xs[64][65];  // [ci][n]
    const int t = threadIdx.x;
    const int b = blockIdx.z;
    const int mat = blockIdx.y >> 2;
    const int co0 = (blockIdx.y & 3) << 6;
    const int n0 = blockIdx.x << 6;
    const float* __restrict__ W = (mat == 0) ? Wq : (mat == 1) ? Wk : Wv;
    float* __restrict__ Y = (mat == 0) ? Q : (mat == 1) ? K : V;
    const int cg = t & 15;   // co group (fast lanes -> coalesced co-major writes)
    const int ng = t >> 4;   // node group
    float acc[4][4];
#pragma unroll
    for (int i = 0; i < 4; ++i)
#pragma unroll
        for (int j = 0; j < 4; ++j) acc[i][j] = 0.f;

    for (int kp = 0; kp < 2; ++kp) {
        const int ci0 = kp << 6;
        const int lr = t >> 4;
        const int lc = (t & 15) << 2;
#pragma unroll
        for (int it = 0; it < 4; ++it) {
            const int r = lr + (it << 4);
            float4 wv = *(const float4*)(W + (size_t)(co0 + r) * CIN + ci0 + lc);
            ws[r][lc] = wv.x; ws[r][lc + 1] = wv.y; ws[r][lc + 2] = wv.z; ws[r][lc + 3] = wv.w;
            float4 xv = *(const float4*)(x + ((size_t)b * CIN + ci0 + r) * NN + n0 + lc);
            xs[r][lc] = xv.x; xs[r][lc + 1] = xv.y; xs[r][lc + 2] = xv.z; xs[r][lc + 3] = xv.w;
        }
        __syncthreads();
#pragma unroll 8
        for (int kk = 0; kk < 64; ++kk) {
            float a_[4], b_[4];
#pragma unroll
            for (int i = 0; i < 4; ++i) a_[i] = ws[cg * 4 + i][kk];
#pragma unroll
            for (int j = 0; j < 4; ++j) b_[j] = xs[kk][ng * 4 + j];
#pragma unroll
            for (int i = 0; i < 4; ++i)
#pragma unroll
                for (int j = 0; j < 4; ++j) acc[i][j] += a_[i] * b_[j];
        }
        __syncthreads();
    }
#pragma unroll
    for (int j = 0; j < 4; ++j) {
        const int n = n0 + ng * 4 + j;
        float4 v = make_float4(acc[0][j], acc[1][j], acc[2][j], acc[3][j]);
        *(float4*)(Y + ((size_t)b * NN + n) * COUT + co0 + cg * 4) = v;
    }
}

// ---------------- Attention ----------------
// one wave per node; lane owns 4 consecutive channels (one head slice)
__global__ __launch_bounds__(256) void attn_kernel(
    const float* __restrict__ Q, const float* __restrict__ K, const float* __restrict__ V,
    const int* __restrict__ edges, float* __restrict__ feat)
{
    __shared__ float s_sc[4][HEADS][KNB];
    __shared__ float s_w[4][HEADS][KNB];
    __shared__ int s_idx[4][KNB];
    const int t = threadIdx.x;
    const int wv = t >> 6;
    const int lane = t & 63;
    const int b = blockIdx.y;
    const int n = (blockIdx.x << 2) + wv;
    const int h = lane >> 3;
    const int dg = lane & 7;
    const size_t base = ((size_t)b * NN + n) * COUT;
    float4 q = *(const float4*)(Q + base + lane * 4);
    const float scl = 0.17677669529663688f;  // 1/sqrt(32)
    q.x *= scl; q.y *= scl; q.z *= scl; q.w *= scl;
    if (lane < KNB) s_idx[wv][lane] = edges[((size_t)b * NN + n) * KNB + lane];
    __syncthreads();
#pragma unroll 4
    for (int j = 0; j < KNB; ++j) {
        const float4 kv = *(const float4*)(K + ((size_t)b * NN + s_idx[wv][j]) * COUT + lane * 4);
        float p = q.x * kv.x + q.y * kv.y + q.z * kv.z + q.w * kv.w;
        p += __shfl_xor(p, 1, 8);
        p += __shfl_xor(p, 2, 8);
        p += __shfl_xor(p, 4, 8);
        if (dg == 0) s_sc[wv][h][j] = p;
    }
    __syncthreads();
#pragma unroll
    for (int g = 0; g < 4; ++g) {
        const int id = g * 64 + lane;
        const int hh = id >> 5, jj = id & 31;
        float val = s_sc[wv][hh][jj];
        float mx = val;
        mx = fmaxf(mx, __shfl_xor(mx, 16, 32));
        mx = fmaxf(mx, __shfl_xor(mx, 8, 32));
        mx = fmaxf(mx, __shfl_xor(mx, 4, 32));
        mx = fmaxf(mx, __shfl_xor(mx, 2, 32));
        mx = fmaxf(mx, __shfl_xor(mx, 1, 32));
        float e = __expf(val - mx);
        float s = e;
        s += __shfl_xor(s, 16, 32);
        s += __shfl_xor(s, 8, 32);
        s += __shfl_xor(s, 4, 32);
        s += __shfl_xor(s, 2, 32);
        s += __shfl_xor(s, 1, 32);
        s_w[wv][hh][jj] = e / s;
    }
    __syncthreads();
    float4 acc = make_float4(0.f, 0.f, 0.f, 0.f);
#pragma unroll 4
    for (int j = 0; j < KNB; ++j) {
        const float w = s_w[wv][h][j];
        const float4 vvv = *(const float4*)(V + ((size_t)b * NN + s_idx[wv][j]) * COUT + lane * 4);
        acc.x += w * vvv.x; acc.y += w * vvv.y; acc.z += w * vvv.z; acc.w += w * vvv.w;
    }
    *(float4*)(feat + base + lane * 4) = acc;  // feat aliases Q: safe, only this block reads Q[n]
}

// ---------------- Wo GEMM ----------------
// o[b][co][n] = sum_c Wo[co][c] * feat[b][n][c]; feat node-major
__global__ __launch_bounds__(256) void wo_kernel(
    const float* __restrict__ feat, const float* __restrict__ Wo, float* __restrict__ o)
{
    __shared__ float as[64][65];  // [co][c]
    __shared__ float bs[64][65];  // [n][c]
    const int t = threadIdx.x;
    const int b = blockIdx.z;
    const int co0 = blockIdx.y << 6;
    const int n0 = blockIdx.x << 6;
    const int nx = t & 15;   // n group (fast -> coalesced n-major writes)
    const int cy = t >> 4;   // co group
    float acc[4][4];
#pragma unroll
    for (int i = 0; i < 4; ++i)
#pragma unroll
        for (int j = 0; j < 4; ++j) acc[i][j] = 0.f;

    for (int c0 = 0; c0 < COUT; c0 += 64) {
        const int lr = t >> 4;
        const int lc = (t & 15) << 2;
#pragma unroll
        for (int it = 0; it < 4; ++it) {
            const int r = lr + (it << 4);
            float4 wv = *(const float4*)(Wo + (size_t)(co0 + r) * COUT + c0 + lc);
            as[r][lc] = wv.x; as[r][lc + 1] = wv.y; as[r][lc + 2] = wv.z; as[r][lc + 3] = wv.w;
            float4 fv = *(const float4*)(feat + ((size_t)b * NN + n0 + r) * COUT + c0 + lc);
            bs[r][lc] = fv.x; bs[r][lc + 1] = fv.y; bs[r][lc + 2] = fv.z; bs[r][lc + 3] = fv.w;
        }
        __syncthreads();
#pragma unroll 8
        for (int kk = 0; kk < 64; ++kk) {
            float a_[4], b_[4];
#pragma unroll
            for (int i = 0; i < 4; ++i) a_[i] = as[cy * 4 + i][kk];
#pragma unroll
            for (int j = 0; j < 4; ++j) b_[j] = bs[nx * 4 + j][kk];
#pragma unroll
            for (int i = 0; i < 4; ++i)
#pragma unroll
                for (int j = 0; j < 4; ++j) acc[i][j] += a_[i] * b_[j];
        }
        __syncthreads();
    }
#pragma unroll
    for (int i = 0; i < 4; ++i) {
        float4 v = make_float4(acc[i][0], acc[i][1], acc[i][2], acc[i][3]);
        *(float4*)(o + ((size_t)b * COUT + co0 + cy * 4 + i) * NN + n0 + nx * 4) = v;
    }
}

// ---------------- BN stats (one block per channel) ----------------
__global__ __launch_bounds__(256) void bn_stats(const float* __restrict__ o, float* __restrict__ stats)
{
    const int co = blockIdx.x;
    const int t = threadIdx.x;
    float s = 0.f, ss = 0.f;
    for (int b = 0; b < BB; ++b) {
        const float* p = o + ((size_t)b * COUT + co) * NN;
        for (int i = t * 4; i < NN; i += 1024) {
            float4 v = *(const float4*)(p + i);
            s += v.x + v.y + v.z + v.w;
            ss += v.x * v.x + v.y * v.y + v.z * v.z + v.w * v.w;
        }
    }
#pragma unroll
    for (int m = 32; m >= 1; m >>= 1) {
        s += __shfl_xor(s, m, 64);
        ss += __shfl_xor(ss, m, 64);
    }
    __shared__ float ps[4], pss[4];
    if ((t & 63) == 0) { ps[t >> 6] = s; pss[t >> 6] = ss; }
    __syncthreads();
    if (t == 0) {
        const float S = ps[0] + ps[1] + ps[2] + ps[3];
        const float SS = pss[0] + pss[1] + pss[2] + pss[3];
        const float inv = 1.f / ((float)BB * NN);
        const float mean = S * inv;
        const float var = SS * inv - mean * mean;
        stats[2 * co] = mean;
        stats[2 * co + 1] = rsqrtf(var + EPSV);
    }
}

// ---------------- BN apply + LeakyReLU ----------------
__global__ __launch_bounds__(256) void bn_apply(
    const float* __restrict__ o, const float* __restrict__ stats,
    const float* __restrict__ gamma, const float* __restrict__ beta,
    float* __restrict__ out)
{
    const size_t i4 = (size_t)blockIdx.x * 256 + threadIdx.x;
    const size_t pos = i4 * 4;
    const int co = (int)((pos / NN) % COUT);
    const float mean = stats[2 * co];
    const float istd = stats[2 * co + 1];
    const float g = gamma[co] * istd;
    const float bt = beta[co] - mean * g;
    float4 v = *(const float4*)(o + pos);
    float4 r;
    r.x = g * v.x + bt; r.x = (r.x >= 0.f) ? r.x : SLOPE * r.x;
    r.y = g * v.y + bt; r.y = (r.y >= 0.f) ? r.y : SLOPE * r.y;
    r.z = g * v.z + bt; r.z = (r.z >= 0.f) ? r.z : SLOPE * r.z;
    r.w = g * v.w + bt; r.w = (r.w >= 0.f) ? r.w : SLOPE * r.w;
    *(float4*)(out + pos) = r;
}

extern "C" void kernel_launch(void* const* d_in, const int* in_sizes, int n_in,
                              void* d_out, int out_size, void* d_ws, size_t ws_size,
                              hipStream_t stream)
{
    const float* x     = (const float*)d_in[0];
    const int*   edges = (const int*)d_in[1];   // harness normalizes ints to int32
    const float* Wq    = (const float*)d_in[2];
    const float* Wk    = (const float*)d_in[3];
    const float* Wv    = (const float*)d_in[4];
    const float* Wo    = (const float*)d_in[5];
    const float* gamma = (const float*)d_in[6];
    const float* beta  = (const float*)d_in[7];
    float* out = (float*)d_out;

    const size_t SZ = (size_t)BB * NN * COUT;  // 8,388,608 floats per buffer
    float* Q     = (float*)d_ws;
    float* K     = Q + SZ;
    float* V     = K + SZ;
    float* stats = V + SZ;
    float* feat  = Q;  // attention output overwrites Q (safe: per-node exclusive)
    float* o     = K;  // Wo output overwrites K (K dead after attention)

    qkv_kernel<<<dim3(NN / 64, 12, BB), 256, 0, stream>>>(x, Wq, Wk, Wv, Q, K, V);
    attn_kernel<<<dim3(NN / 4, BB), 256, 0, stream>>>(Q, K, V, edges, feat);
    wo_kernel<<<dim3(NN / 64, COUT / 64, BB), 256, 0, stream>>>(feat, Wo, o);
    bn_stats<<<dim3(COUT), 256, 0, stream>>>(o, stats);
    bn_apply<<<dim3((unsigned)(SZ / 4 / 256)), 256, 0, stream>>>(o, stats, gamma, beta, out);
}

// Round 4
// 481.919 us; speedup vs baseline: 1.0460x; 1.0460x over previous
//
#include <hip/hip_runtime.h>
#include <math.h>

#define HEADS 8
#define HD 32
#define KNB 32
#define CIN 128
#define COUT 256
#define BB 4
#define NN 8192
#define EPSV 1e-5f
#define SLOPE 0.2f

// ---------------- QKV GEMM ----------------
// x: [B][CIN][N], W: [COUT][CIN]. Output node-major [B][N][COUT].
// 1-D grid 6144 blocks with XCD-affinity decode: all 12 (mat,co) tiles of one
// (b, n-tile) land on the SAME XCD back-to-back -> x tile fetched once per XCD.
__global__ __launch_bounds__(256) void qkv_kernel(
    const float* __restrict__ x,
    const float* __restrict__ Wq, const float* __restrict__ Wk, const float* __restrict__ Wv,
    float* __restrict__ Q, float* __restrict__ K, float* __restrict__ V)
{
    __shared__ float ws[64][68];  // [ci][co]  (transposed W tile; 272B rows, 16B-aligned)
    __shared__ float xs[64][68];  // [ci][n]
    const int t = threadIdx.x;
    const int i = blockIdx.x;
    const int xcd = i & 7;
    const int local = i >> 3;          // 0..767
    const int matco = local % 12;
    const int tl = local / 12;         // 0..63
    const int g = tl * 8 + xcd;        // 0..511
    const int b = g >> 7;
    const int n0 = (g & 127) << 6;
    const int mat = matco >> 2;
    const int co0 = (matco & 3) << 6;
    const float* __restrict__ W = (mat == 0) ? Wq : (mat == 1) ? Wk : Wv;
    float* __restrict__ Y = (mat == 0) ? Q : (mat == 1) ? K : V;
    const int cg = t & 15;   // co group (fast lanes -> coalesced co-major writes)
    const int ng = t >> 4;   // node group
    float acc[4][4];
#pragma unroll
    for (int ii = 0; ii < 4; ++ii)
#pragma unroll
        for (int j = 0; j < 4; ++j) acc[ii][j] = 0.f;

    const int lr = t >> 4;
    const int lc = (t & 15) << 2;
    for (int kp = 0; kp < 2; ++kp) {
        const int ci0 = kp << 6;
#pragma unroll
        for (int it = 0; it < 4; ++it) {
            const int r = lr + (it << 4);
            float4 wv = *(const float4*)(W + (size_t)(co0 + r) * CIN + ci0 + lc);
            ws[lc + 0][r] = wv.x; ws[lc + 1][r] = wv.y; ws[lc + 2][r] = wv.z; ws[lc + 3][r] = wv.w;
            float4 xv = *(const float4*)(x + ((size_t)b * CIN + ci0 + r) * NN + n0 + lc);
            *(float4*)&xs[r][lc] = xv;
        }
        __syncthreads();
#pragma unroll 8
        for (int kk = 0; kk < 64; ++kk) {
            float4 a4 = *(const float4*)&ws[kk][cg * 4];
            float4 b4 = *(const float4*)&xs[kk][ng * 4];
            acc[0][0] += a4.x * b4.x; acc[0][1] += a4.x * b4.y; acc[0][2] += a4.x * b4.z; acc[0][3] += a4.x * b4.w;
            acc[1][0] += a4.y * b4.x; acc[1][1] += a4.y * b4.y; acc[1][2] += a4.y * b4.z; acc[1][3] += a4.y * b4.w;
            acc[2][0] += a4.z * b4.x; acc[2][1] += a4.z * b4.y; acc[2][2] += a4.z * b4.z; acc[2][3] += a4.z * b4.w;
            acc[3][0] += a4.w * b4.x; acc[3][1] += a4.w * b4.y; acc[3][2] += a4.w * b4.z; acc[3][3] += a4.w * b4.w;
        }
        __syncthreads();
    }
#pragma unroll
    for (int j = 0; j < 4; ++j) {
        const int n = n0 + ng * 4 + j;
        float4 v = make_float4(acc[0][j], acc[1][j], acc[2][j], acc[3][j]);
        *(float4*)(Y + ((size_t)b * NN + n) * COUT + co0 + cg * 4) = v;
    }
}

// ---------------- Attention (single-pass online softmax) ----------------
// 1-D grid 8192 blocks; batch pinned to an XCD pair so each L2 sees one batch's
// K+V (16 MB) only. One wave per node; lane owns 4 channels of one head.
__global__ __launch_bounds__(256) void attn_kernel(
    const float* __restrict__ Q, const float* __restrict__ K, const float* __restrict__ V,
    const int* __restrict__ edges, float* __restrict__ feat)
{
    __shared__ int s_idx[4][KNB];
    const int t = threadIdx.x;
    const int wv = t >> 6;
    const int lane = t & 63;
    const int i = blockIdx.x;
    const int xcd = i & 7;
    const int b = xcd >> 1;                    // batch pinned to XCD pair
    const int grp = ((i >> 3) << 1) | (xcd & 1);
    const int n = (grp << 2) + wv;
    const size_t nb = (size_t)b * NN;
    const size_t base = (nb + n) * COUT;
    const int c = lane * 4;

    float4 q = *(const float4*)(Q + base + c);
    const float scl = 0.17677669529663688f;  // 1/sqrt(32)
    q.x *= scl; q.y *= scl; q.z *= scl; q.w *= scl;
    if (lane < KNB) s_idx[wv][lane] = edges[(nb + n) * KNB + lane];
    __syncthreads();

    const float* __restrict__ Kb = K + nb * COUT;
    const float* __restrict__ Vb = V + nb * COUT;

    float4 kb[2], vb[2];
    kb[0] = *(const float4*)(Kb + (size_t)s_idx[wv][0] * COUT + c);
    vb[0] = *(const float4*)(Vb + (size_t)s_idx[wv][0] * COUT + c);
    kb[1] = *(const float4*)(Kb + (size_t)s_idx[wv][1] * COUT + c);
    vb[1] = *(const float4*)(Vb + (size_t)s_idx[wv][1] * COUT + c);

    float m = -1e30f, l = 0.f;
    float4 acc = make_float4(0.f, 0.f, 0.f, 0.f);
#pragma unroll
    for (int j = 0; j < KNB; ++j) {
        float4 kc = kb[j & 1], vc = vb[j & 1];
        if (j + 2 < KNB) {  // prefetch depth 2 (pairs)
            const size_t row = (size_t)s_idx[wv][j + 2] * COUT + c;
            kb[j & 1] = *(const float4*)(Kb + row);
            vb[j & 1] = *(const float4*)(Vb + row);
        }
        float p = q.x * kc.x + q.y * kc.y + q.z * kc.z + q.w * kc.w;
        p += __shfl_xor(p, 1, 8);
        p += __shfl_xor(p, 2, 8);
        p += __shfl_xor(p, 4, 8);       // all 8 lanes of head group hold score j
        const float mn = fmaxf(m, p);
        const float sc = __expf(m - mn);
        const float w = __expf(p - mn);
        l = l * sc + w;
        acc.x = acc.x * sc + w * vc.x;
        acc.y = acc.y * sc + w * vc.y;
        acc.z = acc.z * sc + w * vc.z;
        acc.w = acc.w * sc + w * vc.w;
        m = mn;
    }
    const float inv = 1.0f / l;
    acc.x *= inv; acc.y *= inv; acc.z *= inv; acc.w *= inv;
    *(float4*)(feat + base + c) = acc;  // feat aliases Q: safe, only this block reads Q[n]
}

// ---------------- Wo GEMM ----------------
// o[b][co][n] = sum_c Wo[co][c] * feat[b][n][c]; feat node-major.
// 1-D grid 2048 blocks; 4 co-tiles of one (b,n-tile) on the same XCD.
__global__ __launch_bounds__(256) void wo_kernel(
    const float* __restrict__ feat, const float* __restrict__ Wo, float* __restrict__ o)
{
    __shared__ float as[64][68];  // [c][co]
    __shared__ float bs[64][68];  // [c][n]
    const int t = threadIdx.x;
    const int i = blockIdx.x;
    const int xcd = i & 7;
    const int local = i >> 3;          // 0..255
    const int co0 = (local & 3) << 6;
    const int tl = local >> 2;         // 0..63
    const int g = tl * 8 + xcd;        // 0..511
    const int b = g >> 7;
    const int n0 = (g & 127) << 6;
    const int nx = t & 15;   // n group (fast -> coalesced n-major writes)
    const int cy = t >> 4;   // co group
    float acc[4][4];
#pragma unroll
    for (int ii = 0; ii < 4; ++ii)
#pragma unroll
        for (int j = 0; j < 4; ++j) acc[ii][j] = 0.f;

    const int lr = t >> 4;
    const int lc = (t & 15) << 2;
    for (int c0 = 0; c0 < COUT; c0 += 64) {
#pragma unroll
        for (int it = 0; it < 4; ++it) {
            const int r = lr + (it << 4);
            float4 wv = *(const float4*)(Wo + (size_t)(co0 + r) * COUT + c0 + lc);
            as[lc + 0][r] = wv.x; as[lc + 1][r] = wv.y; as[lc + 2][r] = wv.z; as[lc + 3][r] = wv.w;
            float4 fv = *(const float4*)(feat + ((size_t)b * NN + n0 + r) * COUT + c0 + lc);
            bs[lc + 0][r] = fv.x; bs[lc + 1][r] = fv.y; bs[lc + 2][r] = fv.z; bs[lc + 3][r] = fv.w;
        }
        __syncthreads();
#pragma unroll 8
        for (int kk = 0; kk < 64; ++kk) {
            float4 a4 = *(const float4*)&as[kk][cy * 4];
            float4 b4 = *(const float4*)&bs[kk][nx * 4];
            acc[0][0] += a4.x * b4.x; acc[0][1] += a4.x * b4.y; acc[0][2] += a4.x * b4.z; acc[0][3] += a4.x * b4.w;
            acc[1][0] += a4.y * b4.x; acc[1][1] += a4.y * b4.y; acc[1][2] += a4.y * b4.z; acc[1][3] += a4.y * b4.w;
            acc[2][0] += a4.z * b4.x; acc[2][1] += a4.z * b4.y; acc[2][2] += a4.z * b4.z; acc[2][3] += a4.z * b4.w;
            acc[3][0] += a4.w * b4.x; acc[3][1] += a4.w * b4.y; acc[3][2] += a4.w * b4.z; acc[3][3] += a4.w * b4.w;
        }
        __syncthreads();
    }
#pragma unroll
    for (int ii = 0; ii < 4; ++ii) {
        float4 v = make_float4(acc[ii][0], acc[ii][1], acc[ii][2], acc[ii][3]);
        *(float4*)(o + ((size_t)b * COUT + co0 + cy * 4 + ii) * NN + n0 + nx * 4) = v;
    }
}

// ---------------- BN stats (one block per channel) ----------------
__global__ __launch_bounds__(256) void bn_stats(const float* __restrict__ o, float* __restrict__ stats)
{
    const int co = blockIdx.x;
    const int t = threadIdx.x;
    float s = 0.f, ss = 0.f;
    for (int b = 0; b < BB; ++b) {
        const float* p = o + ((size_t)b * COUT + co) * NN;
        for (int i = t * 4; i < NN; i += 1024) {
            float4 v = *(const float4*)(p + i);
            s += v.x + v.y + v.z + v.w;
            ss += v.x * v.x + v.y * v.y + v.z * v.z + v.w * v.w;
        }
    }
#pragma unroll
    for (int m = 32; m >= 1; m >>= 1) {
        s += __shfl_xor(s, m, 64);
        ss += __shfl_xor(ss, m, 64);
    }
    __shared__ float ps[4], pss[4];
    if ((t & 63) == 0) { ps[t >> 6] = s; pss[t >> 6] = ss; }
    __syncthreads();
    if (t == 0) {
        const float S = ps[0] + ps[1] + ps[2] + ps[3];
        const float SS = pss[0] + pss[1] + pss[2] + pss[3];
        const float inv = 1.f / ((float)BB * NN);
        const float mean = S * inv;
        const float var = SS * inv - mean * mean;
        stats[2 * co] = mean;
        stats[2 * co + 1] = rsqrtf(var + EPSV);
    }
}

// ---------------- BN apply + LeakyReLU ----------------
__global__ __launch_bounds__(256) void bn_apply(
    const float* __restrict__ o, const float* __restrict__ stats,
    const float* __restrict__ gamma, const float* __restrict__ beta,
    float* __restrict__ out)
{
    const size_t i4 = (size_t)blockIdx.x * 256 + threadIdx.x;
    const size_t pos = i4 * 4;
    const int co = (int)((pos / NN) % COUT);
    const float mean = stats[2 * co];
    const float istd = stats[2 * co + 1];
    const float g = gamma[co] * istd;
    const float bt = beta[co] - mean * g;
    float4 v = *(const float4*)(o + pos);
    float4 r;
    r.x = g * v.x + bt; r.x = (r.x >= 0.f) ? r.x : SLOPE * r.x;
    r.y = g * v.y + bt; r.y = (r.y >= 0.f) ? r.y : SLOPE * r.y;
    r.z = g * v.z + bt; r.z = (r.z >= 0.f) ? r.z : SLOPE * r.z;
    r.w = g * v.w + bt; r.w = (r.w >= 0.f) ? r.w : SLOPE * r.w;
    *(float4*)(out + pos) = r;
}

extern "C" void kernel_launch(void* const* d_in, const int* in_sizes, int n_in,
                              void* d_out, int out_size, void* d_ws, size_t ws_size,
                              hipStream_t stream)
{
    const float* x     = (const float*)d_in[0];
    const int*   edges = (const int*)d_in[1];   // harness normalizes ints to int32
    const float* Wq    = (const float*)d_in[2];
    const float* Wk    = (const float*)d_in[3];
    const float* Wv    = (const float*)d_in[4];
    const float* Wo    = (const float*)d_in[5];
    const float* gamma = (const float*)d_in[6];
    const float* beta  = (const float*)d_in[7];
    float* out = (float*)d_out;

    const size_t SZ = (size_t)BB * NN * COUT;  // 8,388,608 floats per buffer
    float* Q     = (float*)d_ws;
    float* K     = Q + SZ;
    float* V     = K + SZ;
    float* stats = V + SZ;
    float* feat  = Q;  // attention output overwrites Q (safe: per-node exclusive)
    float* o     = K;  // Wo output overwrites K (K dead after attention)

    qkv_kernel<<<dim3(12 * (NN / 64) * BB), 256, 0, stream>>>(x, Wq, Wk, Wv, Q, K, V);
    attn_kernel<<<dim3((NN / 4) * BB), 256, 0, stream>>>(Q, K, V, edges, feat);
    wo_kernel<<<dim3(4 * (NN / 64) * BB), 256, 0, stream>>>(feat, Wo, o);
    bn_stats<<<dim3(COUT), 256, 0, stream>>>(o, stats);
    bn_apply<<<dim3((unsigned)(SZ / 4 / 256)), 256, 0, stream>>>(o, stats, gamma, beta, out);
}

// Round 5
// 373.646 us; speedup vs baseline: 1.3490x; 1.2898x over previous
//
#include <hip/hip_runtime.h>
#include <math.h>

#define HEADS 8
#define HD 32
#define KNB 32
#define CIN 128
#define COUT 256
#define BB 4
#define NN 8192
#define EPSV 1e-5f
#define SLOPE 0.2f

typedef unsigned short ushort_t;

__device__ inline ushort_t f2bf(float f) {  // RNE float->bf16
    unsigned u = __float_as_uint(f);
    return (ushort_t)((u + 0x7FFFu + ((u >> 16) & 1u)) >> 16);
}
__device__ inline float bf_lo(unsigned u) { return __uint_as_float(u << 16); }
__device__ inline float bf_hi(unsigned u) { return __uint_as_float(u & 0xFFFF0000u); }

// ---------------- QKV GEMM ----------------
// x: [B][CIN][N], W: [COUT][CIN]. Q fp32 node-major; K,V bf16 node-major.
// 1-D grid 6144 blocks, XCD-affinity decode (kept from r4: non-attn kernels improved).
__global__ __launch_bounds__(256) void qkv_kernel(
    const float* __restrict__ x,
    const float* __restrict__ Wq, const float* __restrict__ Wk, const float* __restrict__ Wv,
    float* __restrict__ Q, ushort_t* __restrict__ Kb, ushort_t* __restrict__ Vb)
{
    __shared__ float ws[64][68];  // [ci][co]
    __shared__ float xs[64][68];  // [ci][n]
    const int t = threadIdx.x;
    const int i = blockIdx.x;
    const int xcd = i & 7;
    const int local = i >> 3;
    const int matco = local % 12;
    const int tl = local / 12;
    const int g = tl * 8 + xcd;
    const int b = g >> 7;
    const int n0 = (g & 127) << 6;
    const int mat = matco >> 2;
    const int co0 = (matco & 3) << 6;
    const float* __restrict__ W = (mat == 0) ? Wq : (mat == 1) ? Wk : Wv;
    const int cg = t & 15;
    const int ng = t >> 4;
    float acc[4][4];
#pragma unroll
    for (int ii = 0; ii < 4; ++ii)
#pragma unroll
        for (int j = 0; j < 4; ++j) acc[ii][j] = 0.f;

    const int lr = t >> 4;
    const int lc = (t & 15) << 2;
    for (int kp = 0; kp < 2; ++kp) {
        const int ci0 = kp << 6;
#pragma unroll
        for (int it = 0; it < 4; ++it) {
            const int r = lr + (it << 4);
            float4 wv = *(const float4*)(W + (size_t)(co0 + r) * CIN + ci0 + lc);
            ws[lc + 0][r] = wv.x; ws[lc + 1][r] = wv.y; ws[lc + 2][r] = wv.z; ws[lc + 3][r] = wv.w;
            float4 xv = *(const float4*)(x + ((size_t)b * CIN + ci0 + r) * NN + n0 + lc);
            *(float4*)&xs[r][lc] = xv;
        }
        __syncthreads();
#pragma unroll 8
        for (int kk = 0; kk < 64; ++kk) {
            float4 a4 = *(const float4*)&ws[kk][cg * 4];
            float4 b4 = *(const float4*)&xs[kk][ng * 4];
            acc[0][0] += a4.x * b4.x; acc[0][1] += a4.x * b4.y; acc[0][2] += a4.x * b4.z; acc[0][3] += a4.x * b4.w;
            acc[1][0] += a4.y * b4.x; acc[1][1] += a4.y * b4.y; acc[1][2] += a4.y * b4.z; acc[1][3] += a4.y * b4.w;
            acc[2][0] += a4.z * b4.x; acc[2][1] += a4.z * b4.y; acc[2][2] += a4.z * b4.z; acc[2][3] += a4.z * b4.w;
            acc[3][0] += a4.w * b4.x; acc[3][1] += a4.w * b4.y; acc[3][2] += a4.w * b4.z; acc[3][3] += a4.w * b4.w;
        }
        __syncthreads();
    }
    if (mat == 0) {
#pragma unroll
        for (int j = 0; j < 4; ++j) {
            const int n = n0 + ng * 4 + j;
            float4 v = make_float4(acc[0][j], acc[1][j], acc[2][j], acc[3][j]);
            *(float4*)(Q + ((size_t)b * NN + n) * COUT + co0 + cg * 4) = v;
        }
    } else {
        ushort_t* __restrict__ Y = (mat == 1) ? Kb : Vb;
#pragma unroll
        for (int j = 0; j < 4; ++j) {
            const int n = n0 + ng * 4 + j;
            ushort4 v;
            v.x = f2bf(acc[0][j]); v.y = f2bf(acc[1][j]);
            v.z = f2bf(acc[2][j]); v.w = f2bf(acc[3][j]);
            *(ushort4*)(Y + ((size_t)b * NN + n) * COUT + co0 + cg * 4) = v;
        }
    }
}

// ---------------- Attention (two-pass, bf16 K/V) ----------------
// grid (N/4, B): natural dispatch order keeps concurrent blocks in one batch ->
// per-phase random universe = 4 MB bf16 (~one XCD L2). One wave per node;
// lane owns 4 channels of one head.
__global__ __launch_bounds__(256) void attn_kernel(
    const float* __restrict__ Q, const ushort_t* __restrict__ K, const ushort_t* __restrict__ V,
    const int* __restrict__ edges, float* __restrict__ feat)
{
    __shared__ float s_sc[4][HEADS][33];  // pad 33: banks (h+j)%32 distinct
    __shared__ float s_w[4][HEADS][33];
    __shared__ int s_idx[4][KNB];
    const int t = threadIdx.x;
    const int wv = t >> 6;
    const int lane = t & 63;
    const int b = blockIdx.y;
    const int n = (blockIdx.x << 2) + wv;
    const int h = lane >> 3;
    const int dg = lane & 7;
    const size_t nb = (size_t)b * NN;
    const size_t base = (nb + n) * COUT;
    const int c = lane * 4;

    float4 q = *(const float4*)(Q + base + c);
    const float scl = 0.17677669529663688f;  // 1/sqrt(32)
    q.x *= scl; q.y *= scl; q.z *= scl; q.w *= scl;
    if (lane < KNB) s_idx[wv][lane] = edges[(nb + n) * KNB + lane];
    __syncthreads();

    const ushort_t* __restrict__ Kp = K + nb * COUT;
    const ushort_t* __restrict__ Vp = V + nb * COUT;

    // ---- K pass: scores ----
#pragma unroll
    for (int j = 0; j < KNB; ++j) {
        const uint2 kv = *(const uint2*)(Kp + (size_t)s_idx[wv][j] * COUT + c);
        float p = q.x * bf_lo(kv.x) + q.y * bf_hi(kv.x) + q.z * bf_lo(kv.y) + q.w * bf_hi(kv.y);
        p += __shfl_xor(p, 1, 8);
        p += __shfl_xor(p, 2, 8);
        p += __shfl_xor(p, 4, 8);
        if (dg == 0) s_sc[wv][h][j] = p;
    }
    __syncthreads();

    // ---- softmax: 256 scores, 4 rounds of 64 lanes, 32-wide groups ----
#pragma unroll
    for (int g = 0; g < 4; ++g) {
        const int id = g * 64 + lane;
        const int hh = id >> 5, jj = id & 31;
        float val = s_sc[wv][hh][jj];
        float mx = val;
        mx = fmaxf(mx, __shfl_xor(mx, 16, 32));
        mx = fmaxf(mx, __shfl_xor(mx, 8, 32));
        mx = fmaxf(mx, __shfl_xor(mx, 4, 32));
        mx = fmaxf(mx, __shfl_xor(mx, 2, 32));
        mx = fmaxf(mx, __shfl_xor(mx, 1, 32));
        float e = __expf(val - mx);
        float s = e;
        s += __shfl_xor(s, 16, 32);
        s += __shfl_xor(s, 8, 32);
        s += __shfl_xor(s, 4, 32);
        s += __shfl_xor(s, 2, 32);
        s += __shfl_xor(s, 1, 32);
        s_w[wv][hh][jj] = e / s;
    }
    __syncthreads();

    // ---- V pass: weighted sum ----
    float4 acc = make_float4(0.f, 0.f, 0.f, 0.f);
#pragma unroll
    for (int j = 0; j < KNB; ++j) {
        const float w = s_w[wv][h][j];
        const uint2 vv = *(const uint2*)(Vp + (size_t)s_idx[wv][j] * COUT + c);
        acc.x += w * bf_lo(vv.x); acc.y += w * bf_hi(vv.x);
        acc.z += w * bf_lo(vv.y); acc.w += w * bf_hi(vv.y);
    }
    *(float4*)(feat + base + c) = acc;  // feat aliases Q: safe, per-node exclusive
}

// ---------------- Wo GEMM ----------------
__global__ __launch_bounds__(256) void wo_kernel(
    const float* __restrict__ feat, const float* __restrict__ Wo, float* __restrict__ o)
{
    __shared__ float as[64][68];  // [c][co]
    __shared__ float bs[64][68];  // [c][n]
    const int t = threadIdx.x;
    const int i = blockIdx.x;
    const int xcd = i & 7;
    const int local = i >> 3;
    const int co0 = (local & 3) << 6;
    const int tl = local >> 2;
    const int g = tl * 8 + xcd;
    const int b = g >> 7;
    const int n0 = (g & 127) << 6;
    const int nx = t & 15;
    const int cy = t >> 4;
    float acc[4][4];
#pragma unroll
    for (int ii = 0; ii < 4; ++ii)
#pragma unroll
        for (int j = 0; j < 4; ++j) acc[ii][j] = 0.f;

    const int lr = t >> 4;
    const int lc = (t & 15) << 2;
    for (int c0 = 0; c0 < COUT; c0 += 64) {
#pragma unroll
        for (int it = 0; it < 4; ++it) {
            const int r = lr + (it << 4);
            float4 wv = *(const float4*)(Wo + (size_t)(co0 + r) * COUT + c0 + lc);
            as[lc + 0][r] = wv.x; as[lc + 1][r] = wv.y; as[lc + 2][r] = wv.z; as[lc + 3][r] = wv.w;
            float4 fv = *(const float4*)(feat + ((size_t)b * NN + n0 + r) * COUT + c0 + lc);
            bs[lc + 0][r] = fv.x; bs[lc + 1][r] = fv.y; bs[lc + 2][r] = fv.z; bs[lc + 3][r] = fv.w;
        }
        __syncthreads();
#pragma unroll 8
        for (int kk = 0; kk < 64; ++kk) {
            float4 a4 = *(const float4*)&as[kk][cy * 4];
            float4 b4 = *(const float4*)&bs[kk][nx * 4];
            acc[0][0] += a4.x * b4.x; acc[0][1] += a4.x * b4.y; acc[0][2] += a4.x * b4.z; acc[0][3] += a4.x * b4.w;
            acc[1][0] += a4.y * b4.x; acc[1][1] += a4.y * b4.y; acc[1][2] += a4.y * b4.z; acc[1][3] += a4.y * b4.w;
            acc[2][0] += a4.z * b4.x; acc[2][1] += a4.z * b4.y; acc[2][2] += a4.z * b4.z; acc[2][3] += a4.z * b4.w;
            acc[3][0] += a4.w * b4.x; acc[3][1] += a4.w * b4.y; acc[3][2] += a4.w * b4.z; acc[3][3] += a4.w * b4.w;
        }
        __syncthreads();
    }
#pragma unroll
    for (int ii = 0; ii < 4; ++ii) {
        float4 v = make_float4(acc[ii][0], acc[ii][1], acc[ii][2], acc[ii][3]);
        *(float4*)(o + ((size_t)b * COUT + co0 + cy * 4 + ii) * NN + n0 + nx * 4) = v;
    }
}

// ---------------- BN stats ----------------
__global__ __launch_bounds__(256) void bn_stats(const float* __restrict__ o, float* __restrict__ stats)
{
    const int co = blockIdx.x;
    const int t = threadIdx.x;
    float s = 0.f, ss = 0.f;
    for (int b = 0; b < BB; ++b) {
        const float* p = o + ((size_t)b * COUT + co) * NN;
        for (int i = t * 4; i < NN; i += 1024) {
            float4 v = *(const float4*)(p + i);
            s += v.x + v.y + v.z + v.w;
            ss += v.x * v.x + v.y * v.y + v.z * v.z + v.w * v.w;
        }
    }
#pragma unroll
    for (int m = 32; m >= 1; m >>= 1) {
        s += __shfl_xor(s, m, 64);
        ss += __shfl_xor(ss, m, 64);
    }
    __shared__ float ps[4], pss[4];
    if ((t & 63) == 0) { ps[t >> 6] = s; pss[t >> 6] = ss; }
    __syncthreads();
    if (t == 0) {
        const float S = ps[0] + ps[1] + ps[2] + ps[3];
        const float SS = pss[0] + pss[1] + pss[2] + pss[3];
        const float inv = 1.f / ((float)BB * NN);
        const float mean = S * inv;
        const float var = SS * inv - mean * mean;
        stats[2 * co] = mean;
        stats[2 * co + 1] = rsqrtf(var + EPSV);
    }
}

// ---------------- BN apply + LeakyReLU ----------------
__global__ __launch_bounds__(256) void bn_apply(
    const float* __restrict__ o, const float* __restrict__ stats,
    const float* __restrict__ gamma, const float* __restrict__ beta,
    float* __restrict__ out)
{
    const size_t i4 = (size_t)blockIdx.x * 256 + threadIdx.x;
    const size_t pos = i4 * 4;
    const int co = (int)((pos / NN) % COUT);
    const float mean = stats[2 * co];
    const float istd = stats[2 * co + 1];
    const float g = gamma[co] * istd;
    const float bt = beta[co] - mean * g;
    float4 v = *(const float4*)(o + pos);
    float4 r;
    r.x = g * v.x + bt; r.x = (r.x >= 0.f) ? r.x : SLOPE * r.x;
    r.y = g * v.y + bt; r.y = (r.y >= 0.f) ? r.y : SLOPE * r.y;
    r.z = g * v.z + bt; r.z = (r.z >= 0.f) ? r.z : SLOPE * r.z;
    r.w = g * v.w + bt; r.w = (r.w >= 0.f) ? r.w : SLOPE * r.w;
    *(float4*)(out + pos) = r;
}

extern "C" void kernel_launch(void* const* d_in, const int* in_sizes, int n_in,
                              void* d_out, int out_size, void* d_ws, size_t ws_size,
                              hipStream_t stream)
{
    const float* x     = (const float*)d_in[0];
    const int*   edges = (const int*)d_in[1];
    const float* Wq    = (const float*)d_in[2];
    const float* Wk    = (const float*)d_in[3];
    const float* Wv    = (const float*)d_in[4];
    const float* Wo    = (const float*)d_in[5];
    const float* gamma = (const float*)d_in[6];
    const float* beta  = (const float*)d_in[7];
    float* out = (float*)d_out;

    const size_t SZ = (size_t)BB * NN * COUT;  // 8,388,608 elements
    float*    Q     = (float*)d_ws;            // SZ f32 (aliased by feat)
    ushort_t* Kb    = (ushort_t*)(Q + SZ);     // SZ bf16
    ushort_t* Vb    = Kb + SZ;                 // SZ bf16
    float*    o     = (float*)(Vb + SZ);       // SZ f32
    float*    stats = o + SZ;                  // 512 f32
    float*    feat  = Q;
    // total: 12*SZ bytes = 100.7 MB

    qkv_kernel<<<dim3(12 * (NN / 64) * BB), 256, 0, stream>>>(x, Wq, Wk, Wv, Q, Kb, Vb);
    attn_kernel<<<dim3(NN / 4, BB), 256, 0, stream>>>(Q, Kb, Vb, edges, feat);
    wo_kernel<<<dim3(4 * (NN / 64) * BB), 256, 0, stream>>>(feat, Wo, o);
    bn_stats<<<dim3(COUT), 256, 0, stream>>>(o, stats);
    bn_apply<<<dim3((unsigned)(SZ / 4 / 256)), 256, 0, stream>>>(o, stats, gamma, beta, out);
}

// Round 6
// 283.712 us; speedup vs baseline: 1.7767x; 1.3170x over previous
//
#include <hip/hip_runtime.h>
#include <math.h>

#define HEADS 8
#define KNB 32
#define CIN 128
#define COUT 256
#define BB 4
#define NN 8192
#define EPSV 1e-5f
#define SLOPE 0.2f

typedef _Float16 h8 __attribute__((ext_vector_type(8)));
typedef _Float16 h4 __attribute__((ext_vector_type(4)));
typedef float f4 __attribute__((ext_vector_type(4)));

// ---------------- QKV GEMM (fp16 MFMA) ----------------
// x: [B][CIN][N] fp32, W: [COUT][CIN] fp32 -> Q/K/V fp16 node-major [B][N][COUT].
// grid 6144 blocks, XCD-affinity decode: 12 (mat,co) tiles of one (b,ntile)
// land consecutively on one XCD -> x tile L2-reused 12x.
__global__ __launch_bounds__(256) void qkv_kernel(
    const float* __restrict__ x,
    const float* __restrict__ Wq, const float* __restrict__ Wk, const float* __restrict__ Wv,
    _Float16* __restrict__ Q, _Float16* __restrict__ K, _Float16* __restrict__ V)
{
    __shared__ _Float16 wl[16][65][8];  // [k/8][co(+pad)][k%8]
    __shared__ _Float16 xl[16][65][8];  // [k/8][n (+pad)][k%8]
    const int t = threadIdx.x;
    const int i = blockIdx.x;
    const int xcd = i & 7;
    const int local = i >> 3;
    const int matco = local % 12;
    const int tl = local / 12;
    const int g = tl * 8 + xcd;
    const int b = g >> 7;
    const int n0 = (g & 127) << 6;
    const int mat = matco >> 2;
    const int co0 = (matco & 3) << 6;
    const float* __restrict__ W = (mat == 0) ? Wq : (mat == 1) ? Wk : Wv;

    // stage W tile 64co x 128k (fp32 -> fp16)
#pragma unroll
    for (int it = 0; it < 8; ++it) {
        const int flat = t + it * 256;        // 2048 float4s
        const int co = flat >> 5;             // 0..63
        const int k4 = (flat & 31) << 2;      // 0..124 step 4
        float4 wv = *(const float4*)(W + (size_t)(co0 + co) * CIN + k4);
        h4 hv; hv[0] = (_Float16)wv.x; hv[1] = (_Float16)wv.y;
        hv[2] = (_Float16)wv.z; hv[3] = (_Float16)wv.w;
        *(h4*)&wl[k4 >> 3][co][k4 & 7] = hv;
    }
    // stage x tile 128k x 64n (fp32 -> fp16, transposed into [k/8][n][k%8])
#pragma unroll
    for (int it = 0; it < 8; ++it) {
        const int flat = t + it * 256;
        const int ci = flat >> 4;             // 0..127
        const int n4 = (flat & 15) << 2;
        float4 xv = *(const float4*)(x + ((size_t)b * CIN + ci) * NN + n0 + n4);
        xl[ci >> 3][n4 + 0][ci & 7] = (_Float16)xv.x;
        xl[ci >> 3][n4 + 1][ci & 7] = (_Float16)xv.y;
        xl[ci >> 3][n4 + 2][ci & 7] = (_Float16)xv.z;
        xl[ci >> 3][n4 + 3][ci & 7] = (_Float16)xv.w;
    }
    __syncthreads();

    const int w = t >> 6, lane = t & 63;
    const int m = lane & 15, ko = lane >> 4;
    f4 acc[4];
#pragma unroll
    for (int j = 0; j < 4; ++j) acc[j] = (f4){0.f, 0.f, 0.f, 0.f};
#pragma unroll
    for (int s = 0; s < 4; ++s) {
        const h8 a = *(const h8*)&wl[s * 4 + ko][w * 16 + m][0];
#pragma unroll
        for (int j = 0; j < 4; ++j) {
            const h8 bb = *(const h8*)&xl[s * 4 + ko][j * 16 + m][0];
            acc[j] = __builtin_amdgcn_mfma_f32_16x16x32_f16(a, bb, acc[j], 0, 0, 0);
        }
    }

    _Float16* __restrict__ Y = (mat == 0) ? Q : (mat == 1) ? K : V;
    const int cob = co0 + w * 16 + (lane >> 4) * 4;   // D: row=(lane>>4)*4+r, col=lane&15
#pragma unroll
    for (int j = 0; j < 4; ++j) {
        const int n = n0 + j * 16 + m;
        h4 hv; hv[0] = (_Float16)acc[j][0]; hv[1] = (_Float16)acc[j][1];
        hv[2] = (_Float16)acc[j][2]; hv[3] = (_Float16)acc[j][3];
        *(h4*)(Y + ((size_t)b * NN + n) * COUT + cob) = hv;
    }
}

// ---------------- Attention (two-pass, fp16 K/V, nt-hinted streaming) ----------------
__global__ __launch_bounds__(256) void attn_kernel(
    const _Float16* __restrict__ Q, const _Float16* __restrict__ K, const _Float16* __restrict__ V,
    const int* __restrict__ edges, _Float16* __restrict__ feat)
{
    __shared__ float s_sc[4][HEADS][33];
    __shared__ float s_w[4][HEADS][33];
    __shared__ int s_idx[4][KNB];
    const int t = threadIdx.x;
    const int wv = t >> 6;
    const int lane = t & 63;
    const int b = blockIdx.y;
    const int n = (blockIdx.x << 2) + wv;
    const int h = lane >> 3;
    const int dg = lane & 7;
    const size_t nb = (size_t)b * NN;
    const size_t base = (nb + n) * COUT;
    const int c = lane * 4;

    const h4 qh = __builtin_nontemporal_load((const h4*)(Q + base + c));
    const float scl = 0.17677669529663688f;  // 1/sqrt(32)
    const float qx = (float)qh[0] * scl, qy = (float)qh[1] * scl;
    const float qz = (float)qh[2] * scl, qw = (float)qh[3] * scl;
    if (lane < KNB) s_idx[wv][lane] = __builtin_nontemporal_load(edges + (nb + n) * KNB + lane);
    __syncthreads();

    const _Float16* __restrict__ Kp = K + nb * COUT;
    const _Float16* __restrict__ Vp = V + nb * COUT;

    // K pass
#pragma unroll
    for (int j = 0; j < KNB; ++j) {
        const h4 kh = *(const h4*)(Kp + (size_t)s_idx[wv][j] * COUT + c);
        float p = qx * (float)kh[0] + qy * (float)kh[1] + qz * (float)kh[2] + qw * (float)kh[3];
        p += __shfl_xor(p, 1, 8);
        p += __shfl_xor(p, 2, 8);
        p += __shfl_xor(p, 4, 8);
        if (dg == 0) s_sc[wv][h][j] = p;
    }
    __syncthreads();

    // softmax
#pragma unroll
    for (int g = 0; g < 4; ++g) {
        const int id = g * 64 + lane;
        const int hh = id >> 5, jj = id & 31;
        float val = s_sc[wv][hh][jj];
        float mx = val;
        mx = fmaxf(mx, __shfl_xor(mx, 16, 32));
        mx = fmaxf(mx, __shfl_xor(mx, 8, 32));
        mx = fmaxf(mx, __shfl_xor(mx, 4, 32));
        mx = fmaxf(mx, __shfl_xor(mx, 2, 32));
        mx = fmaxf(mx, __shfl_xor(mx, 1, 32));
        float e = __expf(val - mx);
        float s = e;
        s += __shfl_xor(s, 16, 32);
        s += __shfl_xor(s, 8, 32);
        s += __shfl_xor(s, 4, 32);
        s += __shfl_xor(s, 2, 32);
        s += __shfl_xor(s, 1, 32);
        s_w[wv][hh][jj] = e / s;
    }
    __syncthreads();

    // V pass
    float ax = 0.f, ay = 0.f, az = 0.f, aw = 0.f;
#pragma unroll
    for (int j = 0; j < KNB; ++j) {
        const float w = s_w[wv][h][j];
        const h4 vh = *(const h4*)(Vp + (size_t)s_idx[wv][j] * COUT + c);
        ax += w * (float)vh[0]; ay += w * (float)vh[1];
        az += w * (float)vh[2]; aw += w * (float)vh[3];
    }
    h4 f; f[0] = (_Float16)ax; f[1] = (_Float16)ay; f[2] = (_Float16)az; f[3] = (_Float16)aw;
    __builtin_nontemporal_store(f, (h4*)(feat + base + c));  // feat aliases Q: per-node exclusive
}

// ---------------- Wo GEMM (fp16 MFMA) ----------------
// o_nm[b][n][co] fp32 = Wo[co][c] * feat[b][n][c]; K=256 in 2 chunks of 128.
__global__ __launch_bounds__(256) void wo_kernel(
    const _Float16* __restrict__ feat, const float* __restrict__ Wo, float* __restrict__ o)
{
    __shared__ _Float16 wl[16][65][8];
    __shared__ _Float16 fl[16][65][8];
    const int t = threadIdx.x;
    const int i = blockIdx.x;
    const int xcd = i & 7;
    const int local = i >> 3;
    const int co0 = (local & 3) << 6;
    const int tl = local >> 2;
    const int g = tl * 8 + xcd;
    const int b = g >> 7;
    const int n0 = (g & 127) << 6;
    const int w = t >> 6, lane = t & 63;
    const int m = lane & 15, ko = lane >> 4;
    f4 acc[4];
#pragma unroll
    for (int j = 0; j < 4; ++j) acc[j] = (f4){0.f, 0.f, 0.f, 0.f};

    for (int c0 = 0; c0 < COUT; c0 += 128) {
#pragma unroll
        for (int it = 0; it < 8; ++it) {
            const int flat = t + it * 256;
            const int co = flat >> 5;
            const int k4 = (flat & 31) << 2;
            float4 wv = *(const float4*)(Wo + (size_t)(co0 + co) * COUT + c0 + k4);
            h4 hv; hv[0] = (_Float16)wv.x; hv[1] = (_Float16)wv.y;
            hv[2] = (_Float16)wv.z; hv[3] = (_Float16)wv.w;
            *(h4*)&wl[k4 >> 3][co][k4 & 7] = hv;
        }
#pragma unroll
        for (int it = 0; it < 4; ++it) {
            const int flat = t + it * 256;   // 1024 h8s = 64n x 16 c8
            const int n = flat >> 4;
            const int c8 = flat & 15;
            const h8 fv = *(const h8*)(feat + ((size_t)b * NN + n0 + n) * COUT + c0 + c8 * 8);
            *(h8*)&fl[c8][n][0] = fv;
        }
        __syncthreads();
#pragma unroll
        for (int s = 0; s < 4; ++s) {
            const h8 a = *(const h8*)&wl[s * 4 + ko][w * 16 + m][0];
#pragma unroll
            for (int j = 0; j < 4; ++j) {
                const h8 bb = *(const h8*)&fl[s * 4 + ko][j * 16 + m][0];
                acc[j] = __builtin_amdgcn_mfma_f32_16x16x32_f16(a, bb, acc[j], 0, 0, 0);
            }
        }
        __syncthreads();
    }

    const int cob = co0 + w * 16 + (lane >> 4) * 4;
#pragma unroll
    for (int j = 0; j < 4; ++j) {
        const int n = n0 + j * 16 + m;
        *(f4*)(o + ((size_t)b * NN + n) * COUT + cob) = acc[j];
    }
}

// ---------------- BN partial sums (o node-major; thread<->channel coalesced) ----------------
__global__ __launch_bounds__(256) void bn_part(const float* __restrict__ o,
                                               float* __restrict__ ps, float* __restrict__ pss)
{
    const int blk = blockIdx.x;      // 512 blocks x 64 rows
    const int co = threadIdx.x;
    float s = 0.f, ss = 0.f;
    const size_t r0 = (size_t)blk * 64;
    for (int r = 0; r < 64; ++r) {
        const float v = o[(r0 + r) * COUT + co];
        s += v; ss += v * v;
    }
    ps[blk * COUT + co] = s;
    pss[blk * COUT + co] = ss;
}

__global__ __launch_bounds__(256) void bn_reduce(const float* __restrict__ ps, const float* __restrict__ pss,
                                                 const float* __restrict__ gamma, const float* __restrict__ beta,
                                                 float* __restrict__ stats)
{
    const int co = threadIdx.x;
    float s = 0.f, ss = 0.f;
    for (int p = 0; p < 512; ++p) { s += ps[p * COUT + co]; ss += pss[p * COUT + co]; }
    const float inv = 1.f / (float)(BB * NN);
    const float mean = s * inv;
    const float var = ss * inv - mean * mean;
    const float istd = rsqrtf(var + EPSV);
    const float sc = gamma[co] * istd;
    stats[co * 2] = sc;
    stats[co * 2 + 1] = beta[co] - mean * sc;
}

// ---------------- BN apply + LeakyReLU + transpose to [b][co][n] ----------------
__global__ __launch_bounds__(256) void bn_apply(const float* __restrict__ o,
                                                const float* __restrict__ stats,
                                                float* __restrict__ out)
{
    __shared__ float tile[64][68];
    const int i = blockIdx.x;           // 2048 = 4b x 4cotile x 128 ntile
    const int nt_ = i & 127, ct = (i >> 7) & 3, b = i >> 9;
    const int n0 = nt_ << 6, co0 = ct << 6;
    const int t = threadIdx.x;
    const int cq = (t & 15) << 2, rg = t >> 4;
#pragma unroll
    for (int it = 0; it < 4; ++it) {
        const int n = rg + it * 16;
        f4 v = *(const f4*)(o + ((size_t)b * NN + n0 + n) * COUT + co0 + cq);
        *(f4*)&tile[n][cq] = v;
    }
    __syncthreads();
    const int n4 = (t & 15) << 2, cg = t >> 4;
#pragma unroll
    for (int it = 0; it < 4; ++it) {
        const int co = cg + it * 16;
        const float sc = stats[(co0 + co) * 2];
        const float sh = stats[(co0 + co) * 2 + 1];
        f4 r;
#pragma unroll
        for (int j = 0; j < 4; ++j) {
            float v = sc * tile[n4 + j][co] + sh;
            r[j] = (v >= 0.f) ? v : SLOPE * v;
        }
        *(f4*)(out + ((size_t)b * COUT + co0 + co) * NN + n0 + n4) = r;
    }
}

extern "C" void kernel_launch(void* const* d_in, const int* in_sizes, int n_in,
                              void* d_out, int out_size, void* d_ws, size_t ws_size,
                              hipStream_t stream)
{
    const float* x     = (const float*)d_in[0];
    const int*   edges = (const int*)d_in[1];
    const float* Wq    = (const float*)d_in[2];
    const float* Wk    = (const float*)d_in[3];
    const float* Wv    = (const float*)d_in[4];
    const float* Wo    = (const float*)d_in[5];
    const float* gamma = (const float*)d_in[6];
    const float* beta  = (const float*)d_in[7];
    float* out = (float*)d_out;

    const size_t SZ = (size_t)BB * NN * COUT;      // 8,388,608 elements
    _Float16* Q    = (_Float16*)d_ws;              // fp16
    _Float16* K    = Q + SZ;
    _Float16* V    = K + SZ;
    float*    o    = (float*)(V + SZ);             // fp32 node-major
    float*    ps   = o + SZ;
    float*    pss  = ps + 512 * COUT;
    float*    stats = pss + 512 * COUT;
    _Float16* feat = Q;                            // alias: per-node exclusive

    qkv_kernel<<<dim3(12 * 128 * BB), 256, 0, stream>>>(x, Wq, Wk, Wv, Q, K, V);
    attn_kernel<<<dim3(NN / 4, BB), 256, 0, stream>>>(Q, K, V, edges, feat);
    wo_kernel<<<dim3(4 * 128 * BB), 256, 0, stream>>>(feat, Wo, o);
    bn_part<<<dim3(512), 256, 0, stream>>>(o, ps, pss);
    bn_reduce<<<dim3(1), 256, 0, stream>>>(ps, pss, gamma, beta, stats);
    bn_apply<<<dim3(2048), 256, 0, stream>>>(o, stats, out);
}